// Round 4
// baseline (180.128 us; speedup 1.0000x reference)
//
#include <hip/hip_runtime.h>

// TrajectoryScore: truncated-exponential mixture scoring + segment sums.
// 64 segments x 100,000 obs. 153.6 MB read-only stream.
//
// v4b: async global->LDS staging pipeline (resubmit of v4 — R3 was an infra
// failure, no counters returned; kernel audit found no hang mechanism).
// R1/R2 proved VGPR-destination loads get re-serialized by the register
// allocator regardless of source scheduling (VGPR stuck at 28/32 => ~1 line
// in flight per wave => 2.5 TB/s delivered). global_load_lds has NO VGPR
// destination: fire-and-forget, vmcnt-counted, cannot be sunk to a use.
// Each wave runs a private 2-slot LDS ring (no block barriers): stage chunk
// j+2, counted-wait vmcnt(2) for chunk j, consume via ds_read_b128. 4 KB per
// wave in flight through every compute phase. Compute, lane mapping, and
// per-thread accumulation order bit-identical to v2/v3 (absmax 0 runs).

constexpr int ELT_BATCH       = 64;
constexpr int OBS_PER_ELT     = 100000;
constexpr int F4_PER_SEG      = OBS_PER_ELT * 3 / 4;   // 75000 float4 per segment per array
constexpr int CHUNK_F4        = 63;                    // 63 f4 = 84 obs per wave-chunk
constexpr int CHUNKS_PER_SEG  = (F4_PER_SEG + CHUNK_F4 - 1) / CHUNK_F4;  // 1191
constexpr int BLOCKS_PER_SEG  = 32;
constexpr int BLOCK           = 256;
constexpr int WAVES_PER_BLOCK = BLOCK / 64;            // 4
constexpr int WAVES_PER_SEG   = BLOCKS_PER_SEG * WAVES_PER_BLOCK;  // 128
constexpr int NSLOT           = 2;                     // per-wave LDS ring depth

typedef const __attribute__((address_space(1))) void g_void;
typedef __attribute__((address_space(3))) void l_void;

__device__ __forceinline__ float wave_reduce_sum(float v) {
    #pragma unroll
    for (int off = 32; off > 0; off >>= 1)
        v += __shfl_down(v, off, 64);
    return v;
}

__device__ __forceinline__ void eval_chunk(
    const float4 a, const float4 b, const int act,
    const int lane, const bool m0, const bool m1,
    const float nli, const float coef, const float omh, const float th,
    float& ll, float& hs)
{
    const float d0 = a.x - b.x, d1 = a.y - b.y, d2 = a.z - b.z, d3 = a.w - b.w;
    const float q0 = d0 * d0, q1 = d1 * d1, q2 = d2 * d2, q3 = d3 * d3;

    // "head" = leading components belonging to the obs straddling from lane-1.
    const float head = m1 ? (q0 + q1) : q0;
    const float hn   = __shfl_down(head, 1, 64);

    // obs A per lane: m0 -> obs 4g = q0+q1+q2 ; m1 -> obs 4g+2 = q2+q3+hn ;
    //                 m2 -> obs 4g+3 = q1+q2+q3.  obs B (m0 only): 4g+1 = q3+hn.
    const float t12 = q1 + q2;
    const float s2A = m0 ? (q0 + t12) : (m1 ? (q2 + q3 + hn) : (t12 + q3));
    const float s2B = q3 + hn;

    const bool lv = lane < act;
    {
        const float e  = __expf(nli * s2A);
        const float ph = coef * e;
        const float p  = ph + omh;
        const float lp = __logf(p);
        const float po = ph / p;
        const bool  cl = (s2A < th) && lv;
        ll += cl ? lp : 0.0f;
        hs += (cl && po > 0.95f) ? po : 0.0f;
    }
    {
        const float e  = __expf(nli * s2B);
        const float ph = coef * e;
        const float p  = ph + omh;
        const float lp = __logf(p);
        const float po = ph / p;
        const bool  cl = (s2B < th) && lv && m0;
        ll += cl ? lp : 0.0f;
        hs += (cl && po > 0.95f) ? po : 0.0f;
    }
}

__global__ __launch_bounds__(BLOCK, 8) void TrajectoryScore_58145267253396_kernel(
    const float4* __restrict__ pred4,
    const float4* __restrict__ obs4,
    const float*  __restrict__ h_arr,
    const float*  __restrict__ lam_arr,
    const float*  __restrict__ th_arr,
    float*        __restrict__ out)
{
    // Per-wave private staging rings: [wave][slot][lane]. ~16 KB/block ->
    // 8 blocks/CU still fit (128 KB of 160 KB).
    __shared__ float4 sp[WAVES_PER_BLOCK][NSLOT][64];
    __shared__ float4 so[WAVES_PER_BLOCK][NSLOT][64];

    const int seg        = blockIdx.x / BLOCKS_PER_SEG;
    const int blk_in_seg = blockIdx.x % BLOCKS_PER_SEG;
    const int tid  = threadIdx.x;
    const int lane = tid & 63;
    const int wave = tid >> 6;
    const int wseg = blk_in_seg * WAVES_PER_BLOCK + wave;   // 0..127 within segment

    // Wave-uniform per-segment params.
    const float h      = h_arr[seg];
    const float lam    = lam_arr[seg];
    const float th     = th_arr[seg];
    const float inv_th = 1.0f / th;
    const float coef   = h * lam / (1.0f - __expf(-lam));
    const float omh    = 1.0f - h;
    const float nli    = -lam * inv_th;

    const int  m  = lane % 3;
    const bool m0 = (m == 0);
    const bool m1 = (m == 1);

    const int seg_f4 = seg * F4_PER_SEG;

    // Chunks owned by this wave: c = wseg + j*128 <= 1190.
    const int NJ = (CHUNKS_PER_SEG - 1 - wseg) / WAVES_PER_SEG + 1;   // 9 or 10

    // Fire-and-forget stage of chunk j into ring slot. HW rule: lane l's 16B
    // lands at (wave-uniform LDS base) + l*16. Addresses clamped -> overshoot
    // chunks broadcast-read the segment's last f4 (harmless, never evaluated).
    auto stage = [&](int j, int slot) {
        const int c   = wseg + j * WAVES_PER_SEG;
        const int idx = seg_f4 + min(c * CHUNK_F4 + lane, F4_PER_SEG - 1);
        __builtin_amdgcn_global_load_lds((g_void*)(pred4 + idx),
                                         (l_void*)(&sp[wave][slot][0]), 16, 0, 0);
        __builtin_amdgcn_global_load_lds((g_void*)(obs4 + idx),
                                         (l_void*)(&so[wave][slot][0]), 16, 0, 0);
    };

    // Prologue: fill both slots (4 loads = 4 KB in flight).
    stage(0, 0);
    stage(1, 1);

    float ll = 0.0f;
    float hs = 0.0f;

    for (int j = 0; j < NJ; ++j) {
        const int slot = j & 1;

        // The 2 youngest outstanding vmem ops at this point are always
        // stage(j+1)'s; waiting to depth 2 therefore guarantees stage(j) has
        // landed while leaving stage(j+1) in flight. Any stray older vector
        // loads (e.g. param loads) only make this more conservative.
        asm volatile("s_waitcnt vmcnt(2)" ::: "memory");

        const float4 a = sp[wave][slot][lane];
        const float4 b = so[wave][slot][lane];

        // ds_reads must retire before the async re-stage overwrites the slot;
        // sched_barrier pins the order against compiler motion.
        asm volatile("s_waitcnt lgkmcnt(0)" ::: "memory");
        __builtin_amdgcn_sched_barrier(0);

        stage(j + 2, slot);   // keep 4 KB in flight through the compute

        const int c   = wseg + j * WAVES_PER_SEG;
        const int act = min(CHUNK_F4, F4_PER_SEG - c * CHUNK_F4);
        eval_chunk(a, b, act, lane, m0, m1, nli, coef, omh, th, ll, hs);
    }

    // Block reduction: 64-lane shuffle, then LDS across the 4 waves.
    ll = wave_reduce_sum(ll);
    hs = wave_reduce_sum(hs);

    __shared__ float sll[WAVES_PER_BLOCK];
    __shared__ float shs[WAVES_PER_BLOCK];
    if (lane == 0) { sll[wave] = ll; shs[wave] = hs; }
    __syncthreads();   // barrier's vmcnt(0) drain also retires stray prefetches
    if (tid == 0) {
        float L = 0.0f, H = 0.0f;
        #pragma unroll
        for (int w = 0; w < WAVES_PER_BLOCK; ++w) { L += sll[w]; H += shs[w]; }
        atomicAdd(&out[seg], L);
        atomicAdd(&out[ELT_BATCH + seg], H);
        atomicAdd(&out[2 * ELT_BATCH + seg], H);  // hits_raw == hits
    }
}

extern "C" void kernel_launch(void* const* d_in, const int* in_sizes, int n_in,
                              void* d_out, int out_size, void* d_ws, size_t ws_size,
                              hipStream_t stream) {
    const float4* pred4   = (const float4*)d_in[0];
    const float4* obs4    = (const float4*)d_in[1];
    const float*  h_arr   = (const float*)d_in[2];
    const float*  lam_arr = (const float*)d_in[3];
    const float*  th_arr  = (const float*)d_in[4];
    float* out = (float*)d_out;

    // Harness poisons d_out to 0xAA before timed replays — zero it ourselves.
    hipMemsetAsync(out, 0, out_size * sizeof(float), stream);

    dim3 grid(ELT_BATCH * BLOCKS_PER_SEG);
    dim3 block(BLOCK);
    TrajectoryScore_58145267253396_kernel<<<grid, block, 0, stream>>>(
        pred4, obs4, h_arr, lam_arr, th_arr, out);
}

// Round 5
// 177.668 us; speedup vs baseline: 1.0138x; 1.0138x over previous
//
#include <hip/hip_runtime.h>

// TrajectoryScore: truncated-exponential mixture scoring + segment sums.
// 64 segments x 100,000 obs. 153.6 MB read-only stream.
//
// v5: stream-topology experiment. R1-R4 falsified per-wave MLP and issue
// structure (strided VGPR, coalesced VGPR, async LDS-staged with counted
// vmcnt(2) all land at 62-64 us, ~2.44 TB/s delivered). The one mechanism all
// variants shared: block-cyclic chunk walks (1 KB touch + 126 KB jump per
// wave) and segments scattered across all 8 XCDs. v5 keeps the v4b async
// global->LDS pipeline bit-for-bit and changes ONLY the topology:
//   (1) each wave owns a CONTIGUOUS run of 9-10 chunks (linear 1-KB march
//       over a private ~10 KB slice of the segment);
//   (2) bijective XCD swizzle (bid&7)*256 + bid>>3 so each XCD's L2 streams
//       a contiguous 8-segment (38 MB) region.
// Math / lane mapping / reduction unchanged (absmax 0 under prior remaps).

constexpr int ELT_BATCH       = 64;
constexpr int OBS_PER_ELT     = 100000;
constexpr int F4_PER_SEG      = OBS_PER_ELT * 3 / 4;   // 75000 float4 per segment per array
constexpr int CHUNK_F4        = 63;                    // 63 f4 = 84 obs per wave-chunk
constexpr int CHUNKS_PER_SEG  = (F4_PER_SEG + CHUNK_F4 - 1) / CHUNK_F4;  // 1191
constexpr int BLOCKS_PER_SEG  = 32;
constexpr int BLOCK           = 256;
constexpr int WAVES_PER_BLOCK = BLOCK / 64;            // 4
constexpr int WAVES_PER_SEG   = BLOCKS_PER_SEG * WAVES_PER_BLOCK;  // 128
constexpr int NSLOT           = 2;                     // per-wave LDS ring depth
// Contiguous ownership: waves 0..38 own 10 chunks, waves 39..127 own 9.
// 39*10 + 89*9 = 1191. Wave w's first chunk: w<39 ? w*10 : 390 + (w-39)*9.
constexpr int SPLIT_W         = 39;

typedef const __attribute__((address_space(1))) void g_void;
typedef __attribute__((address_space(3))) void l_void;

__device__ __forceinline__ float wave_reduce_sum(float v) {
    #pragma unroll
    for (int off = 32; off > 0; off >>= 1)
        v += __shfl_down(v, off, 64);
    return v;
}

__device__ __forceinline__ void eval_chunk(
    const float4 a, const float4 b, const int act,
    const int lane, const bool m0, const bool m1,
    const float nli, const float coef, const float omh, const float th,
    float& ll, float& hs)
{
    const float d0 = a.x - b.x, d1 = a.y - b.y, d2 = a.z - b.z, d3 = a.w - b.w;
    const float q0 = d0 * d0, q1 = d1 * d1, q2 = d2 * d2, q3 = d3 * d3;

    // "head" = leading components belonging to the obs straddling from lane-1.
    const float head = m1 ? (q0 + q1) : q0;
    const float hn   = __shfl_down(head, 1, 64);

    // obs A per lane: m0 -> obs 4g = q0+q1+q2 ; m1 -> obs 4g+2 = q2+q3+hn ;
    //                 m2 -> obs 4g+3 = q1+q2+q3.  obs B (m0 only): 4g+1 = q3+hn.
    const float t12 = q1 + q2;
    const float s2A = m0 ? (q0 + t12) : (m1 ? (q2 + q3 + hn) : (t12 + q3));
    const float s2B = q3 + hn;

    const bool lv = lane < act;
    {
        const float e  = __expf(nli * s2A);
        const float ph = coef * e;
        const float p  = ph + omh;
        const float lp = __logf(p);
        const float po = ph / p;
        const bool  cl = (s2A < th) && lv;
        ll += cl ? lp : 0.0f;
        hs += (cl && po > 0.95f) ? po : 0.0f;
    }
    {
        const float e  = __expf(nli * s2B);
        const float ph = coef * e;
        const float p  = ph + omh;
        const float lp = __logf(p);
        const float po = ph / p;
        const bool  cl = (s2B < th) && lv && m0;
        ll += cl ? lp : 0.0f;
        hs += (cl && po > 0.95f) ? po : 0.0f;
    }
}

__global__ __launch_bounds__(BLOCK, 8) void TrajectoryScore_58145267253396_kernel(
    const float4* __restrict__ pred4,
    const float4* __restrict__ obs4,
    const float*  __restrict__ h_arr,
    const float*  __restrict__ lam_arr,
    const float*  __restrict__ th_arr,
    float*        __restrict__ out)
{
    // Per-wave private staging rings: [wave][slot][lane]. ~16.5 KB/block ->
    // 8 blocks/CU still fit.
    __shared__ float4 sp[WAVES_PER_BLOCK][NSLOT][64];
    __shared__ float4 so[WAVES_PER_BLOCK][NSLOT][64];

    // Bijective XCD swizzle: consecutive dispatch ids round-robin over 8 XCDs;
    // remap so XCD x processes logical blocks [x*256, (x+1)*256) = a contiguous
    // 8-segment (38 MB) region through its own L2. 2048 % 8 == 0 -> bijective.
    const int bid     = blockIdx.x;
    const int logical = (bid & 7) * (ELT_BATCH * BLOCKS_PER_SEG / 8) + (bid >> 3);

    const int seg        = logical / BLOCKS_PER_SEG;
    const int blk_in_seg = logical % BLOCKS_PER_SEG;
    const int tid  = threadIdx.x;
    const int lane = tid & 63;
    const int wave = tid >> 6;
    const int wseg = blk_in_seg * WAVES_PER_BLOCK + wave;   // 0..127 within segment

    // Contiguous chunk ownership for this wave.
    const int cw = (wseg < SPLIT_W) ? wseg * 10 : SPLIT_W * 10 + (wseg - SPLIT_W) * 9;
    const int NJ = (wseg < SPLIT_W) ? 10 : 9;

    // Wave-uniform per-segment params.
    const float h      = h_arr[seg];
    const float lam    = lam_arr[seg];
    const float th     = th_arr[seg];
    const float inv_th = 1.0f / th;
    const float coef   = h * lam / (1.0f - __expf(-lam));
    const float omh    = 1.0f - h;
    const float nli    = -lam * inv_th;

    const int  m  = lane % 3;
    const bool m0 = (m == 0);
    const bool m1 = (m == 1);

    const int seg_f4 = seg * F4_PER_SEG;

    // Fire-and-forget stage of chunk (cw + j) into ring slot. HW rule: lane
    // l's 16B lands at (wave-uniform LDS base) + l*16. Addresses clamped ->
    // overshoot lanes/chunks re-read valid segment bytes (never evaluated).
    auto stage = [&](int j, int slot) {
        const int c   = min(cw + j, CHUNKS_PER_SEG - 1);
        const int idx = seg_f4 + min(c * CHUNK_F4 + lane, F4_PER_SEG - 1);
        __builtin_amdgcn_global_load_lds((g_void*)(pred4 + idx),
                                         (l_void*)(&sp[wave][slot][0]), 16, 0, 0);
        __builtin_amdgcn_global_load_lds((g_void*)(obs4 + idx),
                                         (l_void*)(&so[wave][slot][0]), 16, 0, 0);
    };

    // Prologue: fill both slots (4 loads = 4 KB in flight).
    stage(0, 0);
    stage(1, 1);

    float ll = 0.0f;
    float hs = 0.0f;

    for (int j = 0; j < NJ; ++j) {
        const int slot = j & 1;

        // The 2 youngest outstanding vmem ops here are always stage(j+1)'s;
        // depth-2 wait guarantees stage(j) landed, leaves stage(j+1) in flight.
        asm volatile("s_waitcnt vmcnt(2)" ::: "memory");

        const float4 a = sp[wave][slot][lane];
        const float4 b = so[wave][slot][lane];

        // ds_reads must retire before the async re-stage overwrites the slot.
        asm volatile("s_waitcnt lgkmcnt(0)" ::: "memory");
        __builtin_amdgcn_sched_barrier(0);

        stage(j + 2, slot);   // keep 4 KB in flight through the compute

        const int c   = cw + j;
        const int act = min(CHUNK_F4, F4_PER_SEG - c * CHUNK_F4);
        eval_chunk(a, b, act, lane, m0, m1, nli, coef, omh, th, ll, hs);
    }

    // Block reduction: 64-lane shuffle, then LDS across the 4 waves.
    ll = wave_reduce_sum(ll);
    hs = wave_reduce_sum(hs);

    __shared__ float sll[WAVES_PER_BLOCK];
    __shared__ float shs[WAVES_PER_BLOCK];
    if (lane == 0) { sll[wave] = ll; shs[wave] = hs; }
    __syncthreads();   // barrier's vmcnt(0) drain also retires stray prefetches
    if (tid == 0) {
        float L = 0.0f, H = 0.0f;
        #pragma unroll
        for (int w = 0; w < WAVES_PER_BLOCK; ++w) { L += sll[w]; H += shs[w]; }
        atomicAdd(&out[seg], L);
        atomicAdd(&out[ELT_BATCH + seg], H);
        atomicAdd(&out[2 * ELT_BATCH + seg], H);  // hits_raw == hits
    }
}

extern "C" void kernel_launch(void* const* d_in, const int* in_sizes, int n_in,
                              void* d_out, int out_size, void* d_ws, size_t ws_size,
                              hipStream_t stream) {
    const float4* pred4   = (const float4*)d_in[0];
    const float4* obs4    = (const float4*)d_in[1];
    const float*  h_arr   = (const float*)d_in[2];
    const float*  lam_arr = (const float*)d_in[3];
    const float*  th_arr  = (const float*)d_in[4];
    float* out = (float*)d_out;

    // Harness poisons d_out to 0xAA before timed replays — zero it ourselves.
    hipMemsetAsync(out, 0, out_size * sizeof(float), stream);

    dim3 grid(ELT_BATCH * BLOCKS_PER_SEG);
    dim3 block(BLOCK);
    TrajectoryScore_58145267253396_kernel<<<grid, block, 0, stream>>>(
        pred4, obs4, h_arr, lam_arr, th_arr, out);
}